// Round 4
// baseline (1072.450 us; speedup 1.0000x reference)
//
#include <hip/hip_runtime.h>
#include <math.h>

#define N_TOK 8192
#define DMODEL 512
#define NEXP 8
#define HEXP 1024
#define RHDIM 256
#define KP 4672          // IN_DIM=4611 padded to multiple of 64 (zero-filled)
#define IN_REAL 4611
#define BK 64            // K-tile; one LDS row = 128 B = one cache line
#define NPAIR (N_TOK * 2)
#define MAXT 136         // max 128-row expert tiles (fc2)
#define MAXT2 72         // max 256-row expert tiles (fc1)

typedef unsigned short u16;
typedef __bf16 bf16x8 __attribute__((ext_vector_type(8)));
typedef float f32x4 __attribute__((ext_vector_type(4)));

__device__ inline u16 f2bf(float f) {
    union { float f; unsigned u; } x; x.f = f;
    unsigned r = x.u + 0x7FFFu + ((x.u >> 16) & 1u);   // round-to-nearest-even
    return (u16)(r >> 16);
}
__device__ inline float bf2f(u16 u) {
    union { unsigned u; float f; } x; x.u = ((unsigned)u) << 16;
    return x.f;
}
__device__ inline float gelu_exact(float v) {
    return 0.5f * v * (1.f + erff(v * 0.70710678118654752440f));
}

// async global->LDS, 16B per lane; lds base wave-uniform, lane lands at base + lane*16
__device__ inline void async_cp16(const u16* g, u16* l) {
    __builtin_amdgcn_global_load_lds(
        (const __attribute__((address_space(1))) unsigned int*)g,
        (__attribute__((address_space(3))) unsigned int*)l, 16, 0, 0);
}

// ---- multi-stat block reduction for 512-thread blocks: v[i] -> block sum ----
template<int M>
__device__ inline void breduce(float (&v)[M], int tid, float* red) {
    #pragma unroll
    for (int o = 32; o > 0; o >>= 1)
        #pragma unroll
        for (int i = 0; i < M; i++) v[i] += __shfl_xor(v[i], o);
    __syncthreads();                        // guard red[] reuse
    if ((tid & 63) == 0) {
        #pragma unroll
        for (int i = 0; i < M; i++) red[(tid >> 6) * M + i] = v[i];
    }
    __syncthreads();
    if (tid < M) {
        float S = 0.f;
        #pragma unroll
        for (int w8 = 0; w8 < 8; w8++) S += red[w8 * M + tid];
        red[96 + tid] = S;
    }
    __syncthreads();
    #pragma unroll
    for (int i = 0; i < M; i++) v[i] = red[96 + i];
}

// ---- block stats for 512-thread blocks: returns (mean, rsqrt(var+eps)) ----
__device__ inline float2 bstats512(float v, int tid, float* red) {
    float s = v, q = v * v;
    #pragma unroll
    for (int o = 32; o > 0; o >>= 1) {
        s += __shfl_xor(s, o);
        q += __shfl_xor(q, o);
    }
    __syncthreads();
    if ((tid & 63) == 0) { red[(tid >> 6) * 2] = s; red[(tid >> 6) * 2 + 1] = q; }
    __syncthreads();
    if (tid == 0) {
        float S = 0.f, Q = 0.f;
        #pragma unroll
        for (int i = 0; i < 8; i++) { S += red[i * 2]; Q += red[i * 2 + 1]; }
        float m = S * (1.f / 512.f);
        float var = fmaxf(Q * (1.f / 512.f) - m * m, 0.f);
        red[16] = m;
        red[17] = rsqrtf(var + 1e-5f);
    }
    __syncthreads();
    return make_float2(red[16], red[17]);
}

// ---- transpose fp32 [K0,H] -> bf16 [H,KPd] (zero-fill k>=K0), optional hi/lo split ----
__global__ __launch_bounds__(256)
void transpose_f32_bf16(const float* __restrict__ src, u16* __restrict__ dhi, u16* __restrict__ dlo,
                        int K0, int KPd, int H, size_t sbatch, size_t dbatch) {
    __shared__ float tile[32][33];
    int bz = blockIdx.z;
    src += (size_t)bz * sbatch;
    size_t dob = (size_t)bz * dbatch;
    int k0 = blockIdx.x * 32, h0 = blockIdx.y * 32;
    int tx = threadIdx.x, ty = threadIdx.y;
    for (int i = ty; i < 32; i += 8) {
        int k = k0 + i;
        tile[i][tx] = (k < K0) ? src[(size_t)k * H + (h0 + tx)] : 0.f;
    }
    __syncthreads();
    for (int i = ty; i < 32; i += 8) {
        int h = h0 + i, k = k0 + tx;
        float v = tile[tx][i];
        u16 hv = f2bf(v);
        dhi[dob + (size_t)h * KPd + k] = hv;
        if (dlo) dlo[dob + (size_t)h * KPd + k] = f2bf(v - bf2f(hv));
    }
}

// ---- build fusion input x (9 LayerNorms + mask), emit bf16 hi/lo split ----
__global__ __launch_bounds__(512)
void build_x(const float* __restrict__ z1, const float* __restrict__ z2, const float* __restrict__ z3,
             const float* __restrict__ mask,
             const float* __restrict__ ln_g, const float* __restrict__ ln_b,
             const float* __restrict__ lnp_g, const float* __restrict__ lnp_b,
             u16* __restrict__ xhi, u16* __restrict__ xlo) {
    __shared__ float red[108];
    int n = blockIdx.x, d = threadIdx.x;
    float a = z1[(size_t)n * DMODEL + d];
    float b = z2[(size_t)n * DMODEL + d];
    float c = z3[(size_t)n * DMODEL + d];
    float gg = ln_g[d], bb = ln_b[d], pg = lnp_g[d], pb = lnp_b[d];
    size_t base = (size_t)n * KP;

    auto emit = [&](int seg, float v) {
        u16 h = f2bf(v);
        xhi[base + seg * DMODEL + d] = h;
        xlo[base + seg * DMODEL + d] = f2bf(v - bf2f(h));
    };
    auto lnv = [](float v, float s, float q, float g, float bo) {
        float m = s * (1.f / 512.f);
        float var = fmaxf(q * (1.f / 512.f) - m * m, 0.f);
        return (v - m) * rsqrtf(var + 1e-5f) * g + bo;
    };
    // phase 1: three base LNs in one reduction round
    float v6[6] = {a, a * a, b, b * b, c, c * c};
    breduce<6>(v6, d, red);
    float z1n = lnv(a, v6[0], v6[1], gg, bb);
    float z2n = lnv(b, v6[2], v6[3], gg, bb);
    float z3n = lnv(c, v6[4], v6[5], gg, bb);
    emit(0, z1n); emit(1, z2n); emit(2, z3n);
    // phase 2: six pair LNs in one reduction round
    float d12 = z1n - z2n, d13 = z1n - z3n, d23 = z2n - z3n;
    float p12 = z1n * z2n, p13 = z1n * z3n, p23 = z2n * z3n;
    float v12[12] = {d12, d12 * d12, d13, d13 * d13, d23, d23 * d23,
                     p12, p12 * p12, p13, p13 * p13, p23, p23 * p23};
    breduce<12>(v12, d, red);
    emit(3, lnv(d12, v12[0], v12[1], pg, pb));
    emit(4, lnv(d13, v12[2], v12[3], pg, pb));
    emit(5, lnv(d23, v12[4], v12[5], pg, pb));
    emit(6, lnv(p12, v12[6], v12[7], pg, pb));
    emit(7, lnv(p13, v12[8], v12[9], pg, pb));
    emit(8, lnv(p23, v12[10], v12[11], pg, pb));
    if (d < 64) {   // mask cols 4608..4610 + zero pad 4611..4671
        int col = 9 * DMODEL + d;
        float v = (d < 3) ? mask[(size_t)n * 3 + d] : 0.f;
        u16 h = f2bf(v);
        xhi[base + col] = h;
        xlo[base + col] = f2bf(v - bf2f(h));
    }
}

// ============ r2-proven 128x256 bf16 GEMM, BK=64, 512 thr (8 waves, 2Mx4N) ============
// (kept for router_fc1 / expert_fc2 — the 991-us banked config)
#define GEMM_DEFS                                                             \
    int t = threadIdx.x;                                                      \
    int lane = t & 63, w = t >> 6;                                            \
    int r8 = lane >> 3;                                                       \
    int ce = ((lane & 7) ^ r8) * 8;       /* swizzled global chunk, elems */  \
    int fr = lane & 15, q4 = lane >> 4;                                       \
    int wm = (w & 1) * 64, wn = (w >> 1) * 64;                                \
    f32x4 acc[4][4];                                                          \
    { f32x4 z4 = {0.f, 0.f, 0.f, 0.f};                                        \
      _Pragma("unroll") for (int i = 0; i < 4; i++)                           \
      _Pragma("unroll") for (int j = 0; j < 4; j++) acc[i][j] = z4; }         \
    u16 *lAp[2], *lBp[4];                                                     \
    _Pragma("unroll") for (int i = 0; i < 2; i++)                             \
        lAp[i] = lA + (w * 16 + 8 * i) * BK;                                  \
    _Pragma("unroll") for (int i = 0; i < 4; i++)                             \
        lBp[i] = lB + (w * 32 + 8 * i) * BK;

#define GEMM_KSTEP                                                            \
        __syncthreads();                                                      \
        _Pragma("unroll") for (int i = 0; i < 2; i++) {                       \
            async_cp16(gA[i], lAp[i]); gA[i] += BK;                           \
        }                                                                     \
        _Pragma("unroll") for (int i = 0; i < 4; i++) {                       \
            async_cp16(gB[i], lBp[i]); gB[i] += BK;                           \
        }                                                                     \
        __syncthreads();                                                      \
        _Pragma("unroll") for (int ks = 0; ks < 2; ks++) {                    \
            bf16x8 af[4], bfr[4];                                             \
            int cofs = (((q4 + ks * 4) ^ (fr & 7)) * 8);                      \
            _Pragma("unroll") for (int i = 0; i < 4; i++)                     \
                af[i] = *(const bf16x8*)&lA[(wm + i * 16 + fr) * BK + cofs];  \
            _Pragma("unroll") for (int j = 0; j < 4; j++)                     \
                bfr[j] = *(const bf16x8*)&lB[(wn + j * 16 + fr) * BK + cofs]; \
            _Pragma("unroll") for (int i = 0; i < 4; i++)                     \
            _Pragma("unroll") for (int j = 0; j < 4; j++)                     \
                acc[i][j] = __builtin_amdgcn_mfma_f32_16x16x32_bf16(af[i], bfr[j], acc[i][j], 0, 0, 0); \
        }

// ---- router fc1: partial GEMM; 1D grid 384: mt = b&63, part = b>>6 ----
__global__ __launch_bounds__(512, 4)
void router_fc1(const u16* __restrict__ xhi, const u16* __restrict__ xlo,
                const u16* __restrict__ rw1hi, const u16* __restrict__ rw1lo,
                float* __restrict__ rpart) {
    int mt = blockIdx.x & 63, part = blockIdx.x >> 6;
    int region = part >> 1, half = part & 1;
    const u16* A = (region == 2) ? xlo : xhi;        // hh: hi*hi, hl: hi*lo, lh: lo*hi
    const u16* B = (region == 1) ? rw1lo : rw1hi;
    int kbase = half ? 2304 : 0;
    int klen  = half ? 2368 : 2304;                  // both divisible by 64

    __shared__ u16 lA[128 * BK];
    __shared__ u16 lB[256 * BK];
    GEMM_DEFS

    const u16* gA[2]; const u16* gB[4];
    #pragma unroll
    for (int i = 0; i < 2; i++)
        gA[i] = A + (size_t)(mt * 128 + w * 16 + 8 * i + r8) * KP + kbase + ce;
    #pragma unroll
    for (int i = 0; i < 4; i++)
        gB[i] = B + (size_t)(w * 32 + 8 * i + r8) * KP + kbase + ce;

    for (int k0 = 0; k0 < klen; k0 += BK) {
        GEMM_KSTEP
    }
    float* outp = rpart + (size_t)part * ((size_t)N_TOK * RHDIM);
    int cn = lane & 15;
    #pragma unroll
    for (int i = 0; i < 4; i++)
        #pragma unroll
        for (int rr = 0; rr < 4; rr++) {
            int mg = mt * 128 + wm + i * 16 + q4 * 4 + rr;
            #pragma unroll
            for (int j = 0; j < 4; j++)
                outp[(size_t)mg * RHDIM + wn + j * 16 + cn] = acc[i][j][rr];
        }
}

// ---- fused: partial-sum + bias + gelu + logits + top-2 + gates + scatter (1 wave/token) ----
__global__ __launch_bounds__(256)
void logits_topk(const float* __restrict__ rpart, const float* __restrict__ r_b1,
                 const float* __restrict__ r_w2, const float* __restrict__ r_b2,
                 const float* __restrict__ log_temp,
                 float* __restrict__ pgate, int* __restrict__ pexp,
                 int* __restrict__ lists, int* __restrict__ counts) {
    int t = threadIdx.x, wave = t >> 6, lane = t & 63;
    int n = blockIdx.x * 4 + wave;
    // each lane owns rh cols lane*4..lane*4+3
    float4 v = {0.f, 0.f, 0.f, 0.f};
    #pragma unroll
    for (int p = 0; p < 6; p++) {
        float4 s = ((const float4*)(rpart + (size_t)p * ((size_t)N_TOK * RHDIM) + (size_t)n * RHDIM))[lane];
        v.x += s.x; v.y += s.y; v.z += s.z; v.w += s.w;
    }
    float4 b1 = ((const float4*)r_b1)[lane];
    float rh0 = gelu_exact(v.x + b1.x);
    float rh1 = gelu_exact(v.y + b1.y);
    float rh2 = gelu_exact(v.z + b1.z);
    float rh3 = gelu_exact(v.w + b1.w);
    int k = lane * 4;
    float p8[8];
    #pragma unroll
    for (int e = 0; e < 8; e++)
        p8[e] = rh0 * r_w2[(k + 0) * 8 + e] + rh1 * r_w2[(k + 1) * 8 + e]
              + rh2 * r_w2[(k + 2) * 8 + e] + rh3 * r_w2[(k + 3) * 8 + e];
    #pragma unroll
    for (int o = 32; o > 0; o >>= 1)
        #pragma unroll
        for (int e = 0; e < 8; e++) p8[e] += __shfl_xor(p8[e], o);
    if (lane == 0) {
        float temp = fminf(fmaxf(expf(log_temp[0]), 1e-3f), 100.f);
        float l[8];
        #pragma unroll
        for (int e = 0; e < 8; e++) l[e] = (p8[e] + r_b2[e]) / temp;
        int i1 = 0;
        #pragma unroll
        for (int i = 1; i < 8; i++) if (l[i] > l[i1]) i1 = i;   // first-occurrence max (matches top_k)
        int i2 = (i1 == 0) ? 1 : 0;
        #pragma unroll
        for (int i = 0; i < 8; i++) if (i != i1 && l[i] > l[i2]) i2 = i;
        float p = expf(l[i2] - l[i1]);
        float g1 = 1.f / (1.f + p);
        float g2 = p / (1.f + p);
        pgate[n * 2] = g1;     pexp[n * 2] = i1;
        pgate[n * 2 + 1] = g2; pexp[n * 2 + 1] = i2;
        int pos1 = atomicAdd(&counts[i1], 1);
        lists[(size_t)i1 * N_TOK + pos1] = n * 2;
        int pos2 = atomicAdd(&counts[i2], 1);
        lists[(size_t)i2 * N_TOK + pos2] = n * 2 + 1;
    }
}

// ---- tile scheduler: counts -> compact (e,mt) lists for 128-row (fc2) and 256-row (fc1) ----
__global__ void sched_tiles(const int* __restrict__ counts, int* __restrict__ tiles,
                            int* __restrict__ tiles2) {
    if (threadIdx.x == 0) {
        int tcount = 0;
        for (int e = 0; e < NEXP; e++) {
            int nt = (counts[e] + 127) >> 7;
            for (int mt = 0; mt < nt; mt++) tiles[tcount++] = (e << 16) | mt;
        }
        for (; tcount < MAXT; tcount++) tiles[tcount] = -1;   // sentinel
    }
    if (threadIdx.x == 1) {
        int tcount = 0;
        for (int e = 0; e < NEXP; e++) {
            int nt = (counts[e] + 255) >> 8;
            for (int mt = 0; mt < nt; mt++) tiles2[tcount++] = (e << 16) | mt;
        }
        for (; tcount < MAXT2; tcount++) tiles2[tcount] = -1;
    }
}

// ======= expert fc1: 256x256 tile, BK=64, double-buffered counted-vmcnt pipeline =======
// gathered [cnt,KP] x [KP,1024] bf16 GEMM + bias + gelu -> eh bf16.
// T3+T4 (learn_hip m218): per K-step, issue next tile's 8 global_load_lds FIRST, then
// s_waitcnt vmcnt(8) — waits ONLY the previous tile's 8 loads; the 8 just issued stay in
// flight ACROSS the barrier and land under this K-step's 24 ds_read + 64 MFMA (~600 cy).
// Never drains vmcnt to 0 in the loop. Overwrite hazard closed by the end-of-step barrier
// (every wave's ds_reads of buf cur are consumed by its MFMAs before it arrives).
// Tail K-step dummy-restages to keep exactly 16 loads outstanding for the vmcnt(8) count.
// 8 waves 2Mx4N: per-wave C = 128x64 = acc[8][4] (128 AGPR; ~220 unified regs < 256 cap
// at 2 waves/SIMD). LDS 2 x (32K A + 32K B) = 128 KB -> 1 block/CU.
// Staging/swizzle identical math to the proven kernels (conflict-free, PMC=0):
// wave w stages A rows [w*32,+32) and B rows [w*32,+32), 4 cp16 each; lane l -> row
// +8i+(l>>3), global chunk ((l&7)^(l>>3)); LDS chunk c of row r holds global chunk
// c^(r&7); frag read chunk (q4+4ks)^(fr&7).
#define TSZ (256 * BK)

__global__ __launch_bounds__(512, 2)
void expert_fc1(const u16* __restrict__ xhi, const u16* __restrict__ w1t,
                const float* __restrict__ e_b1, const int* __restrict__ lists,
                const int* __restrict__ counts, const int* __restrict__ tiles2,
                u16* __restrict__ eh) {
    int nt = blockIdx.x & 3, ti = blockIdx.x >> 2;
    int info = tiles2[ti];
    if (info < 0) return;
    int e = info >> 16, mt = info & 0xFFFF;
    int cnt = counts[e];

    __shared__ u16 lA[2 * TSZ];
    __shared__ u16 lB[2 * TSZ];
    __shared__ int rows[256];
    int tt = threadIdx.x;
    if (tt < 256) {
        int m = mt * 256 + tt;
        rows[tt] = lists[(size_t)e * N_TOK + (m < cnt ? m : 0)];   // clamp tail to valid entry
    }
    __syncthreads();

    int lane = tt & 63, w = tt >> 6;
    int r8 = lane >> 3;
    int ce = ((lane & 7) ^ r8) * 8;       // swizzled global chunk, elems
    int fr = lane & 15, q4 = lane >> 4;
    int wm = (w & 1) * 128, wn = (w >> 1) * 64;

    f32x4 acc[8][4];
    { f32x4 z4 = {0.f, 0.f, 0.f, 0.f};
      #pragma unroll
      for (int i = 0; i < 8; i++)
          #pragma unroll
          for (int j = 0; j < 4; j++) acc[i][j] = z4; }

    u16 *sA[4], *sB[4];
    #pragma unroll
    for (int i = 0; i < 4; i++) {
        sA[i] = lA + (w * 32 + 8 * i) * BK;
        sB[i] = lB + (w * 32 + 8 * i) * BK;
    }
    const u16* wb = w1t + (size_t)e * HEXP * KP + (size_t)(nt * 256) * KP;
    const u16* gA[4]; const u16* gB[4];
    #pragma unroll
    for (int i = 0; i < 4; i++) {
        gA[i] = xhi + (size_t)(rows[w * 32 + 8 * i + r8] >> 1) * KP + ce;
        gB[i] = wb + (size_t)(w * 32 + 8 * i + r8) * KP + ce;
    }

    // prologue: stage K-tile 0 into buf 0 (8 loads/wave)
    #pragma unroll
    for (int i = 0; i < 4; i++) {
        async_cp16(gA[i], sA[i]); async_cp16(gB[i], sB[i]);
        gA[i] += BK; gB[i] += BK;
    }

    const int NT = KP / BK;   // 73
    int cur = 0;
    for (int kt = 0; kt < NT; kt++) {
        int nb = cur ^ 1;
        if (kt + 1 < NT) {
            #pragma unroll
            for (int i = 0; i < 4; i++) {
                async_cp16(gA[i], sA[i] + nb * TSZ); async_cp16(gB[i], sB[i] + nb * TSZ);
                gA[i] += BK; gB[i] += BK;
            }
        } else {   // dummy restage of last tile: keeps 16 outstanding so vmcnt(8) waits cur's
            #pragma unroll
            for (int i = 0; i < 4; i++) {
                async_cp16(gA[i] - BK, sA[i] + nb * TSZ); async_cp16(gB[i] - BK, sB[i] + nb * TSZ);
            }
        }
        asm volatile("s_waitcnt vmcnt(8)" ::: "memory");   // prev tile landed; 8 stay in flight
        __builtin_amdgcn_s_barrier();
        __builtin_amdgcn_sched_barrier(0);
        const u16* cA = lA + cur * TSZ;
        const u16* cB = lB + cur * TSZ;
        #pragma unroll
        for (int ks = 0; ks < 2; ks++) {
            bf16x8 af[8]; bf16x8 bfr[4];
            int cofs = ((q4 + ks * 4) ^ (fr & 7)) * 8;
            #pragma unroll
            for (int j = 0; j < 4; j++)
                bfr[j] = *(const bf16x8*)&cB[(wn + j * 16 + fr) * BK + cofs];
            #pragma unroll
            for (int i = 0; i < 8; i++)
                af[i] = *(const bf16x8*)&cA[(wm + i * 16 + fr) * BK + cofs];
            __builtin_amdgcn_s_setprio(1);
            #pragma unroll
            for (int i = 0; i < 8; i++)
                #pragma unroll
                for (int j = 0; j < 4; j++)
                    acc[i][j] = __builtin_amdgcn_mfma_f32_16x16x32_bf16(af[i], bfr[j], acc[i][j], 0, 0, 0);
            __builtin_amdgcn_s_setprio(0);
        }
        __builtin_amdgcn_s_barrier();   // all waves done reading buf cur -> safe to overwrite
        cur = nb;
    }

    int cn = lane & 15;
    float b1v[4];
    #pragma unroll
    for (int j = 0; j < 4; j++)
        b1v[j] = e_b1[(size_t)e * HEXP + nt * 256 + wn + j * 16 + cn];
    #pragma unroll
    for (int i = 0; i < 8; i++)
        #pragma unroll
        for (int rr = 0; rr < 4; rr++) {
            int ml = wm + i * 16 + q4 * 4 + rr;
            int mg = mt * 256 + ml;
            if (mg < cnt) {
                int entry = rows[ml];
                #pragma unroll
                for (int j = 0; j < 4; j++) {
                    int col = nt * 256 + wn + j * 16 + cn;
                    float v = acc[i][j][rr] + b1v[j];
                    eh[(size_t)entry * HEXP + col] = f2bf(gelu_exact(v));
                }
            }
        }
}

// ---- expert fc2: gathered [cnt,1024] x [1024,512] bf16 GEMM -> per-slot fp32 outs ----
// 1D grid MAXT*2: nt = b&1, ti = b>>1   (r2-banked version)
__global__ __launch_bounds__(512, 4)
void expert_fc2(const u16* __restrict__ eh, const u16* __restrict__ w2t,
                const int* __restrict__ lists, const int* __restrict__ counts,
                const int* __restrict__ tiles, float* __restrict__ outs) {
    int nt = blockIdx.x & 1, ti = blockIdx.x >> 1;
    int info = tiles[ti];
    if (info < 0) return;
    int e = info >> 16, mt = info & 0xFFFF;
    int cnt = counts[e];

    __shared__ u16 lA[128 * BK];
    __shared__ u16 lB[256 * BK];
    __shared__ int rows[128];
    int tt = threadIdx.x;
    if (tt < 128) {
        int m = mt * 128 + tt;
        rows[tt] = lists[(size_t)e * N_TOK + (m < cnt ? m : 0)];
    }
    __syncthreads();

    GEMM_DEFS

    const u16* wb = w2t + (size_t)e * DMODEL * HEXP + (size_t)(nt * 256) * HEXP;
    const u16* gA[2]; const u16* gB[4];
    #pragma unroll
    for (int i = 0; i < 2; i++)
        gA[i] = eh + (size_t)rows[w * 16 + 8 * i + r8] * HEXP + ce;
    #pragma unroll
    for (int i = 0; i < 4; i++)
        gB[i] = wb + (size_t)(w * 32 + 8 * i + r8) * HEXP + ce;

    for (int k0 = 0; k0 < HEXP; k0 += BK) {
        GEMM_KSTEP
    }
    int cn = lane & 15;
    #pragma unroll
    for (int i = 0; i < 4; i++)
        #pragma unroll
        for (int rr = 0; rr < 4; rr++) {
            int ml = wm + i * 16 + q4 * 4 + rr;
            int mg = mt * 128 + ml;
            if (mg < cnt) {
                int entry = rows[ml];
                #pragma unroll
                for (int j = 0; j < 4; j++) {
                    int col = nt * 256 + wn + j * 16 + cn;
                    outs[(size_t)entry * DMODEL + col] = acc[i][j][rr];
                }
            }
        }
}

// ---- combine: gate*(outs+b2) + masked residual + final LN ----
__global__ __launch_bounds__(512)
void combine_ln(const float* __restrict__ outs, const float* __restrict__ pgate,
                const int* __restrict__ pexp, const float* __restrict__ e_b2,
                const float* __restrict__ mask, const u16* __restrict__ xhi,
                const u16* __restrict__ xlo, const float* __restrict__ oln_g,
                const float* __restrict__ oln_b, float* __restrict__ out) {
    __shared__ float red[18];
    int n = blockIdx.x, d = threadIdx.x;
    float g0 = pgate[n * 2], g1 = pgate[n * 2 + 1];
    int e0 = pexp[n * 2], e1 = pexp[n * 2 + 1];
    float o = g0 * (outs[(size_t)(n * 2) * DMODEL + d] + e_b2[(size_t)e0 * DMODEL + d])
            + g1 * (outs[(size_t)(n * 2 + 1) * DMODEL + d] + e_b2[(size_t)e1 * DMODEL + d]);
    float m0 = mask[n * 3 + 0], m1 = mask[n * 3 + 1], m2 = mask[n * 3 + 2];
    float denom = fmaxf(m0 + m1 + m2, 1.f);
    size_t xb = (size_t)n * KP;
    float z1n = bf2f(xhi[xb + d]) + bf2f(xlo[xb + d]);                       // hi+lo = fp32-exact
    float z2n = bf2f(xhi[xb + DMODEL + d]) + bf2f(xlo[xb + DMODEL + d]);
    float z3n = bf2f(xhi[xb + 2 * DMODEL + d]) + bf2f(xlo[xb + 2 * DMODEL + d]);
    float z = o + (m0 * z1n + m1 * z2n + m2 * z3n) / denom;
    float2 st = bstats512(z, d, red);
    out[(size_t)n * DMODEL + d] = (z - st.x) * st.y * oln_g[d] + oln_b[d];
}

extern "C" void kernel_launch(void* const* d_in, const int* in_sizes, int n_in,
                              void* d_out, int out_size, void* d_ws, size_t ws_size,
                              hipStream_t stream) {
    (void)in_sizes; (void)n_in; (void)out_size; (void)ws_size;
    const float* z1       = (const float*)d_in[0];
    const float* z2       = (const float*)d_in[1];
    const float* z3       = (const float*)d_in[2];
    const float* mask     = (const float*)d_in[3];
    const float* ln_g     = (const float*)d_in[4];
    const float* ln_b     = (const float*)d_in[5];
    const float* lnp_g    = (const float*)d_in[6];
    const float* lnp_b    = (const float*)d_in[7];
    const float* oln_g    = (const float*)d_in[8];
    const float* oln_b    = (const float*)d_in[9];
    const float* r_w1     = (const float*)d_in[10];
    const float* r_b1     = (const float*)d_in[11];
    const float* r_w2     = (const float*)d_in[12];
    const float* r_b2     = (const float*)d_in[13];
    const float* log_temp = (const float*)d_in[14];
    const float* e_w1     = (const float*)d_in[15];
    const float* e_b1     = (const float*)d_in[16];
    const float* e_w2     = (const float*)d_in[17];
    const float* e_b2     = (const float*)d_in[18];
    float* out = (float*)d_out;

    char* p = (char*)d_ws;
    auto carve = [&](size_t bytes) { char* r = p; p += (bytes + 255) & ~(size_t)255; return r; };
    u16*   xhi    = (u16*)carve((size_t)N_TOK * KP * 2);
    u16*   xlo    = (u16*)carve((size_t)N_TOK * KP * 2);
    u16*   w1t    = (u16*)carve((size_t)NEXP * HEXP * KP * 2);
    u16*   w2t    = (u16*)carve((size_t)NEXP * DMODEL * HEXP * 2);
    u16*   rw1hi  = (u16*)carve((size_t)RHDIM * KP * 2);
    u16*   rw1lo  = (u16*)carve((size_t)RHDIM * KP * 2);
    float* rpart  = (float*)carve((size_t)6 * N_TOK * RHDIM * 4);
    u16*   eh     = (u16*)carve((size_t)NPAIR * HEXP * 2);
    float* outsb  = (float*)carve((size_t)NPAIR * DMODEL * 4);
    float* pgate  = (float*)carve((size_t)NPAIR * 4);
    int*   pexp   = (int*)carve((size_t)NPAIR * 4);
    int*   lists  = (int*)carve((size_t)NEXP * N_TOK * 4);
    int*   counts = (int*)carve(256);
    int*   tiles  = (int*)carve(MAXT * 4);
    int*   tiles2 = (int*)carve(MAXT2 * 4);

    dim3 tb(32, 8);
    transpose_f32_bf16<<<dim3(KP / 32, HEXP / 32, NEXP), tb, 0, stream>>>(
        e_w1, w1t, (u16*)nullptr, IN_REAL, KP, HEXP, (size_t)IN_REAL * HEXP, (size_t)HEXP * KP);
    transpose_f32_bf16<<<dim3(HEXP / 32, DMODEL / 32, NEXP), tb, 0, stream>>>(
        e_w2, w2t, (u16*)nullptr, HEXP, HEXP, DMODEL, (size_t)HEXP * DMODEL, (size_t)DMODEL * HEXP);
    transpose_f32_bf16<<<dim3(KP / 32, RHDIM / 32, 1), tb, 0, stream>>>(
        r_w1, rw1hi, rw1lo, IN_REAL, KP, RHDIM, (size_t)0, (size_t)0);

    build_x<<<N_TOK, 512, 0, stream>>>(z1, z2, z3, mask, ln_g, ln_b, lnp_g, lnp_b, xhi, xlo);

    router_fc1<<<384, 512, 0, stream>>>(xhi, xlo, rw1hi, rw1lo, rpart);

    hipMemsetAsync(counts, 0, 256, stream);
    logits_topk<<<N_TOK / 4, 256, 0, stream>>>(rpart, r_b1, r_w2, r_b2, log_temp,
                                               pgate, pexp, lists, counts);
    sched_tiles<<<1, 64, 0, stream>>>(counts, tiles, tiles2);

    expert_fc1<<<MAXT2 * 4, 512, 0, stream>>>(xhi, w1t, e_b1, lists, counts, tiles2, eh);
    expert_fc2<<<MAXT * 2, 512, 0, stream>>>(eh, w2t, lists, counts, tiles, outsb);

    combine_ln<<<N_TOK, 512, 0, stream>>>(outsb, pgate, pexp, e_b2, mask, xhi, xlo, oln_g, oln_b, out);
}

// Round 5
// 978.048 us; speedup vs baseline: 1.0965x; 1.0965x over previous
//
#include <hip/hip_runtime.h>
#include <math.h>

#define N_TOK 8192
#define DMODEL 512
#define NEXP 8
#define HEXP 1024
#define RHDIM 256
#define KP 4672          // IN_DIM=4611 padded to multiple of 64 (zero-filled)
#define IN_REAL 4611
#define BK 64            // K-tile; one LDS row = 128 B = one cache line
#define NPAIR (N_TOK * 2)
#define MAXT 136         // max expert tiles

typedef unsigned short u16;
typedef __bf16 bf16x8 __attribute__((ext_vector_type(8)));
typedef float f32x4 __attribute__((ext_vector_type(4)));

__device__ inline u16 f2bf(float f) {
    union { float f; unsigned u; } x; x.f = f;
    unsigned r = x.u + 0x7FFFu + ((x.u >> 16) & 1u);   // round-to-nearest-even
    return (u16)(r >> 16);
}
__device__ inline float bf2f(u16 u) {
    union { unsigned u; float f; } x; x.u = ((unsigned)u) << 16;
    return x.f;
}
__device__ inline float gelu_exact(float v) {
    return 0.5f * v * (1.f + erff(v * 0.70710678118654752440f));
}

// async global->LDS, 16B per lane; lds base wave-uniform, lane lands at base + lane*16
__device__ inline void async_cp16(const u16* g, u16* l) {
    __builtin_amdgcn_global_load_lds(
        (const __attribute__((address_space(1))) unsigned int*)g,
        (__attribute__((address_space(3))) unsigned int*)l, 16, 0, 0);
}

// ---- multi-stat block reduction for 512-thread blocks: v[i] -> block sum ----
template<int M>
__device__ inline void breduce(float (&v)[M], int tid, float* red) {
    #pragma unroll
    for (int o = 32; o > 0; o >>= 1)
        #pragma unroll
        for (int i = 0; i < M; i++) v[i] += __shfl_xor(v[i], o);
    __syncthreads();                        // guard red[] reuse
    if ((tid & 63) == 0) {
        #pragma unroll
        for (int i = 0; i < M; i++) red[(tid >> 6) * M + i] = v[i];
    }
    __syncthreads();
    if (tid < M) {
        float S = 0.f;
        #pragma unroll
        for (int w8 = 0; w8 < 8; w8++) S += red[w8 * M + tid];
        red[96 + tid] = S;
    }
    __syncthreads();
    #pragma unroll
    for (int i = 0; i < M; i++) v[i] = red[96 + i];
}

// ---- block stats for 512-thread blocks: returns (mean, rsqrt(var+eps)) ----
__device__ inline float2 bstats512(float v, int tid, float* red) {
    float s = v, q = v * v;
    #pragma unroll
    for (int o = 32; o > 0; o >>= 1) {
        s += __shfl_xor(s, o);
        q += __shfl_xor(q, o);
    }
    __syncthreads();
    if ((tid & 63) == 0) { red[(tid >> 6) * 2] = s; red[(tid >> 6) * 2 + 1] = q; }
    __syncthreads();
    if (tid == 0) {
        float S = 0.f, Q = 0.f;
        #pragma unroll
        for (int i = 0; i < 8; i++) { S += red[i * 2]; Q += red[i * 2 + 1]; }
        float m = S * (1.f / 512.f);
        float var = fmaxf(Q * (1.f / 512.f) - m * m, 0.f);
        red[16] = m;
        red[17] = rsqrtf(var + 1e-5f);
    }
    __syncthreads();
    return make_float2(red[16], red[17]);
}

// ---- transpose fp32 [K0,H] -> bf16 [H,KPd] (zero-fill k>=K0), optional hi/lo split ----
__global__ __launch_bounds__(256)
void transpose_f32_bf16(const float* __restrict__ src, u16* __restrict__ dhi, u16* __restrict__ dlo,
                        int K0, int KPd, int H, size_t sbatch, size_t dbatch) {
    __shared__ float tile[32][33];
    int bz = blockIdx.z;
    src += (size_t)bz * sbatch;
    size_t dob = (size_t)bz * dbatch;
    int k0 = blockIdx.x * 32, h0 = blockIdx.y * 32;
    int tx = threadIdx.x, ty = threadIdx.y;
    for (int i = ty; i < 32; i += 8) {
        int k = k0 + i;
        tile[i][tx] = (k < K0) ? src[(size_t)k * H + (h0 + tx)] : 0.f;
    }
    __syncthreads();
    for (int i = ty; i < 32; i += 8) {
        int h = h0 + i, k = k0 + tx;
        float v = tile[tx][i];
        u16 hv = f2bf(v);
        dhi[dob + (size_t)h * KPd + k] = hv;
        if (dlo) dlo[dob + (size_t)h * KPd + k] = f2bf(v - bf2f(hv));
    }
}

// ---- build fusion input x (9 LayerNorms + mask), emit bf16 hi/lo split ----
__global__ __launch_bounds__(512)
void build_x(const float* __restrict__ z1, const float* __restrict__ z2, const float* __restrict__ z3,
             const float* __restrict__ mask,
             const float* __restrict__ ln_g, const float* __restrict__ ln_b,
             const float* __restrict__ lnp_g, const float* __restrict__ lnp_b,
             u16* __restrict__ xhi, u16* __restrict__ xlo) {
    __shared__ float red[108];
    int n = blockIdx.x, d = threadIdx.x;
    float a = z1[(size_t)n * DMODEL + d];
    float b = z2[(size_t)n * DMODEL + d];
    float c = z3[(size_t)n * DMODEL + d];
    float gg = ln_g[d], bb = ln_b[d], pg = lnp_g[d], pb = lnp_b[d];
    size_t base = (size_t)n * KP;

    auto emit = [&](int seg, float v) {
        u16 h = f2bf(v);
        xhi[base + seg * DMODEL + d] = h;
        xlo[base + seg * DMODEL + d] = f2bf(v - bf2f(h));
    };
    auto lnv = [](float v, float s, float q, float g, float bo) {
        float m = s * (1.f / 512.f);
        float var = fmaxf(q * (1.f / 512.f) - m * m, 0.f);
        return (v - m) * rsqrtf(var + 1e-5f) * g + bo;
    };
    // phase 1: three base LNs in one reduction round
    float v6[6] = {a, a * a, b, b * b, c, c * c};
    breduce<6>(v6, d, red);
    float z1n = lnv(a, v6[0], v6[1], gg, bb);
    float z2n = lnv(b, v6[2], v6[3], gg, bb);
    float z3n = lnv(c, v6[4], v6[5], gg, bb);
    emit(0, z1n); emit(1, z2n); emit(2, z3n);
    // phase 2: six pair LNs in one reduction round
    float d12 = z1n - z2n, d13 = z1n - z3n, d23 = z2n - z3n;
    float p12 = z1n * z2n, p13 = z1n * z3n, p23 = z2n * z3n;
    float v12[12] = {d12, d12 * d12, d13, d13 * d13, d23, d23 * d23,
                     p12, p12 * p12, p13, p13 * p13, p23, p23 * p23};
    breduce<12>(v12, d, red);
    emit(3, lnv(d12, v12[0], v12[1], pg, pb));
    emit(4, lnv(d13, v12[2], v12[3], pg, pb));
    emit(5, lnv(d23, v12[4], v12[5], pg, pb));
    emit(6, lnv(p12, v12[6], v12[7], pg, pb));
    emit(7, lnv(p13, v12[8], v12[9], pg, pb));
    emit(8, lnv(p23, v12[10], v12[11], pg, pb));
    if (d < 64) {   // mask cols 4608..4610 + zero pad 4611..4671
        int col = 9 * DMODEL + d;
        float v = (d < 3) ? mask[(size_t)n * 3 + d] : 0.f;
        u16 h = f2bf(v);
        xhi[base + col] = h;
        xlo[base + col] = f2bf(v - bf2f(h));
    }
}

// ========== r0-proven 128x128 bf16 GEMM, BK=64, 256 threads (4 waves, 2x2) ==========
// Best-measured fc1 config (253 us): multi-block residency (~4 blk/CU) beats every
// intra-block pipeline variant tried (r1-r4: 280/306/354 us). LDS rows 64 elems = 128 B.
// XOR swizzle: LDS chunk c holds global chunk c ^ (row&7). Staging: wave w stages rows
// [w*32, w*32+32), 4 cp16 each for A and B; lane l -> row +8i+(l>>3), global chunk
// ((l&7)^(l>>3)). Fragment read chunk (q ^ (fr&7)). Waves 2x2: wm=(w&1)*64, wn=(w>>1)*64.
// A/B-frag: [r=lane&15][k=(lane>>4)*8+j]; C/D: row=(lane>>4)*4+reg, col=lane&15.
#define GEMM_DEFS4                                                            \
    int t = threadIdx.x;                                                      \
    int lane = t & 63, w = t >> 6;                                            \
    int r8 = lane >> 3;                                                       \
    int ce = ((lane & 7) ^ r8) * 8;       /* swizzled global chunk, elems */  \
    int fr = lane & 15, q4 = lane >> 4;                                       \
    int wm = (w & 1) * 64, wn = (w >> 1) * 64;                                \
    f32x4 acc[4][4];                                                          \
    { f32x4 z4 = {0.f, 0.f, 0.f, 0.f};                                        \
      _Pragma("unroll") for (int i = 0; i < 4; i++)                           \
      _Pragma("unroll") for (int j = 0; j < 4; j++) acc[i][j] = z4; }         \
    u16 *lAp[4], *lBp[4];                                                     \
    _Pragma("unroll") for (int i = 0; i < 4; i++) {                           \
        lAp[i] = lA + (w * 32 + 8 * i) * BK;                                  \
        lBp[i] = lB + (w * 32 + 8 * i) * BK;                                  \
    }

#define GEMM_KSTEP4                                                           \
        __syncthreads();                                                      \
        _Pragma("unroll") for (int i = 0; i < 4; i++) {                       \
            async_cp16(gA[i], lAp[i]); async_cp16(gB[i], lBp[i]);             \
            gA[i] += BK; gB[i] += BK;                                         \
        }                                                                     \
        __syncthreads();                                                      \
        _Pragma("unroll") for (int ks = 0; ks < 2; ks++) {                    \
            bf16x8 af[4], bfr[4];                                             \
            int cofs = (((q4 + ks * 4) ^ (fr & 7)) * 8);                      \
            _Pragma("unroll") for (int i = 0; i < 4; i++)                     \
                af[i] = *(const bf16x8*)&lA[(wm + i * 16 + fr) * BK + cofs];  \
            _Pragma("unroll") for (int j = 0; j < 4; j++)                     \
                bfr[j] = *(const bf16x8*)&lB[(wn + j * 16 + fr) * BK + cofs]; \
            _Pragma("unroll") for (int i = 0; i < 4; i++)                     \
            _Pragma("unroll") for (int j = 0; j < 4; j++)                     \
                acc[i][j] = __builtin_amdgcn_mfma_f32_16x16x32_bf16(af[i], bfr[j], acc[i][j], 0, 0, 0); \
        }

// ===== r2-proven 128x256 bf16 GEMM, BK=64, 512 threads (8 waves, 2Mx4N) =====
// (router_fc1 / expert_fc2 — components of the 991-us best run)
#define GEMM_DEFS8                                                            \
    int t = threadIdx.x;                                                      \
    int lane = t & 63, w = t >> 6;                                            \
    int r8 = lane >> 3;                                                       \
    int ce = ((lane & 7) ^ r8) * 8;       /* swizzled global chunk, elems */  \
    int fr = lane & 15, q4 = lane >> 4;                                       \
    int wm = (w & 1) * 64, wn = (w >> 1) * 64;                                \
    f32x4 acc[4][4];                                                          \
    { f32x4 z4 = {0.f, 0.f, 0.f, 0.f};                                        \
      _Pragma("unroll") for (int i = 0; i < 4; i++)                           \
      _Pragma("unroll") for (int j = 0; j < 4; j++) acc[i][j] = z4; }         \
    u16 *lAp[2], *lBp[4];                                                     \
    _Pragma("unroll") for (int i = 0; i < 2; i++)                             \
        lAp[i] = lA + (w * 16 + 8 * i) * BK;                                  \
    _Pragma("unroll") for (int i = 0; i < 4; i++)                             \
        lBp[i] = lB + (w * 32 + 8 * i) * BK;

#define GEMM_KSTEP8                                                           \
        __syncthreads();                                                      \
        _Pragma("unroll") for (int i = 0; i < 2; i++) {                       \
            async_cp16(gA[i], lAp[i]); gA[i] += BK;                           \
        }                                                                     \
        _Pragma("unroll") for (int i = 0; i < 4; i++) {                       \
            async_cp16(gB[i], lBp[i]); gB[i] += BK;                           \
        }                                                                     \
        __syncthreads();                                                      \
        _Pragma("unroll") for (int ks = 0; ks < 2; ks++) {                    \
            bf16x8 af[4], bfr[4];                                             \
            int cofs = (((q4 + ks * 4) ^ (fr & 7)) * 8);                      \
            _Pragma("unroll") for (int i = 0; i < 4; i++)                     \
                af[i] = *(const bf16x8*)&lA[(wm + i * 16 + fr) * BK + cofs];  \
            _Pragma("unroll") for (int j = 0; j < 4; j++)                     \
                bfr[j] = *(const bf16x8*)&lB[(wn + j * 16 + fr) * BK + cofs]; \
            _Pragma("unroll") for (int i = 0; i < 4; i++)                     \
            _Pragma("unroll") for (int j = 0; j < 4; j++)                     \
                acc[i][j] = __builtin_amdgcn_mfma_f32_16x16x32_bf16(af[i], bfr[j], acc[i][j], 0, 0, 0); \
        }

// ---- router fc1: partial GEMM; 1D grid 384: mt = b&63, part = b>>6 ----
// BN=256 = full RHDIM, so each A-tile is staged exactly once per part.
__global__ __launch_bounds__(512, 4)
void router_fc1(const u16* __restrict__ xhi, const u16* __restrict__ xlo,
                const u16* __restrict__ rw1hi, const u16* __restrict__ rw1lo,
                float* __restrict__ rpart) {
    int mt = blockIdx.x & 63, part = blockIdx.x >> 6;
    int region = part >> 1, half = part & 1;
    const u16* A = (region == 2) ? xlo : xhi;        // hh: hi*hi, hl: hi*lo, lh: lo*hi
    const u16* B = (region == 1) ? rw1lo : rw1hi;
    int kbase = half ? 2304 : 0;
    int klen  = half ? 2368 : 2304;                  // both divisible by 64

    __shared__ u16 lA[128 * BK];
    __shared__ u16 lB[256 * BK];
    GEMM_DEFS8

    const u16* gA[2]; const u16* gB[4];
    #pragma unroll
    for (int i = 0; i < 2; i++)
        gA[i] = A + (size_t)(mt * 128 + w * 16 + 8 * i + r8) * KP + kbase + ce;
    #pragma unroll
    for (int i = 0; i < 4; i++)
        gB[i] = B + (size_t)(w * 32 + 8 * i + r8) * KP + kbase + ce;

    for (int k0 = 0; k0 < klen; k0 += BK) {
        GEMM_KSTEP8
    }
    float* outp = rpart + (size_t)part * ((size_t)N_TOK * RHDIM);
    int cn = lane & 15;
    #pragma unroll
    for (int i = 0; i < 4; i++)
        #pragma unroll
        for (int rr = 0; rr < 4; rr++) {
            int mg = mt * 128 + wm + i * 16 + q4 * 4 + rr;
            #pragma unroll
            for (int j = 0; j < 4; j++)
                outp[(size_t)mg * RHDIM + wn + j * 16 + cn] = acc[i][j][rr];
        }
}

// ---- fused: partial-sum + bias + gelu + logits + top-2 + gates + scatter (1 wave/token) ----
__global__ __launch_bounds__(256)
void logits_topk(const float* __restrict__ rpart, const float* __restrict__ r_b1,
                 const float* __restrict__ r_w2, const float* __restrict__ r_b2,
                 const float* __restrict__ log_temp,
                 float* __restrict__ pgate, int* __restrict__ pexp,
                 int* __restrict__ lists, int* __restrict__ counts) {
    int t = threadIdx.x, wave = t >> 6, lane = t & 63;
    int n = blockIdx.x * 4 + wave;
    // each lane owns rh cols lane*4..lane*4+3
    float4 v = {0.f, 0.f, 0.f, 0.f};
    #pragma unroll
    for (int p = 0; p < 6; p++) {
        float4 s = ((const float4*)(rpart + (size_t)p * ((size_t)N_TOK * RHDIM) + (size_t)n * RHDIM))[lane];
        v.x += s.x; v.y += s.y; v.z += s.z; v.w += s.w;
    }
    float4 b1 = ((const float4*)r_b1)[lane];
    float rh0 = gelu_exact(v.x + b1.x);
    float rh1 = gelu_exact(v.y + b1.y);
    float rh2 = gelu_exact(v.z + b1.z);
    float rh3 = gelu_exact(v.w + b1.w);
    int k = lane * 4;
    float p8[8];
    #pragma unroll
    for (int e = 0; e < 8; e++)
        p8[e] = rh0 * r_w2[(k + 0) * 8 + e] + rh1 * r_w2[(k + 1) * 8 + e]
              + rh2 * r_w2[(k + 2) * 8 + e] + rh3 * r_w2[(k + 3) * 8 + e];
    #pragma unroll
    for (int o = 32; o > 0; o >>= 1)
        #pragma unroll
        for (int e = 0; e < 8; e++) p8[e] += __shfl_xor(p8[e], o);
    if (lane == 0) {
        float temp = fminf(fmaxf(expf(log_temp[0]), 1e-3f), 100.f);
        float l[8];
        #pragma unroll
        for (int e = 0; e < 8; e++) l[e] = (p8[e] + r_b2[e]) / temp;
        int i1 = 0;
        #pragma unroll
        for (int i = 1; i < 8; i++) if (l[i] > l[i1]) i1 = i;   // first-occurrence max (matches top_k)
        int i2 = (i1 == 0) ? 1 : 0;
        #pragma unroll
        for (int i = 0; i < 8; i++) if (i != i1 && l[i] > l[i2]) i2 = i;
        float p = expf(l[i2] - l[i1]);
        float g1 = 1.f / (1.f + p);
        float g2 = p / (1.f + p);
        pgate[n * 2] = g1;     pexp[n * 2] = i1;
        pgate[n * 2 + 1] = g2; pexp[n * 2 + 1] = i2;
        int pos1 = atomicAdd(&counts[i1], 1);
        lists[(size_t)i1 * N_TOK + pos1] = n * 2;
        int pos2 = atomicAdd(&counts[i2], 1);
        lists[(size_t)i2 * N_TOK + pos2] = n * 2 + 1;
    }
}

// ---- tile scheduler: counts -> compact (e,mt) list, expert-major ----
// expert-major + nt-in-low-bits grid => same-XCD neighbors share expert B-slice (L2 reuse)
__global__ void sched_tiles(const int* __restrict__ counts, int* __restrict__ tiles) {
    if (threadIdx.x == 0) {
        int tcount = 0;
        for (int e = 0; e < NEXP; e++) {
            int nt = (counts[e] + 127) >> 7;
            for (int mt = 0; mt < nt; mt++) tiles[tcount++] = (e << 16) | mt;
        }
        for (; tcount < MAXT; tcount++) tiles[tcount] = -1;   // sentinel
    }
}

// ---- expert fc1: gathered [cnt,KP] x [KP,1024] bf16 GEMM, gelu -> eh bf16 ----
// 1D grid MAXT*8: nt = b&7, ti = b>>3  (blocks 8 apart: same XCD, same nt, next tile)
__global__ __launch_bounds__(256, 4)
void expert_fc1(const u16* __restrict__ xhi, const u16* __restrict__ w1t,
                const float* __restrict__ e_b1, const int* __restrict__ lists,
                const int* __restrict__ counts, const int* __restrict__ tiles,
                u16* __restrict__ eh) {
    int nt = blockIdx.x & 7, ti = blockIdx.x >> 3;
    int info = tiles[ti];
    if (info < 0) return;
    int e = info >> 16, mt = info & 0xFFFF;
    int cnt = counts[e];

    __shared__ u16 lA[128 * BK];
    __shared__ u16 lB[128 * BK];
    __shared__ int rows[128];
    int tt = threadIdx.x;
    if (tt < 128) {
        int m = mt * 128 + tt;
        rows[tt] = lists[(size_t)e * N_TOK + (m < cnt ? m : 0)];   // clamp tail to valid entry
    }
    __syncthreads();

    GEMM_DEFS4

    const u16* wb = w1t + (size_t)e * HEXP * KP + (size_t)(nt * 128) * KP;
    const u16* gA[4]; const u16* gB[4];
    #pragma unroll
    for (int i = 0; i < 4; i++) {
        gA[i] = xhi + (size_t)(rows[w * 32 + 8 * i + r8] >> 1) * KP + ce;
        gB[i] = wb + (size_t)(w * 32 + 8 * i + r8) * KP + ce;
    }

    for (int k0 = 0; k0 < KP; k0 += BK) {
        GEMM_KSTEP4
    }
    int cn = lane & 15;
    #pragma unroll
    for (int i = 0; i < 4; i++)
        #pragma unroll
        for (int rr = 0; rr < 4; rr++) {
            int ml = wm + i * 16 + q4 * 4 + rr;
            int mg = mt * 128 + ml;
            if (mg < cnt) {
                int entry = rows[ml];
                #pragma unroll
                for (int j = 0; j < 4; j++) {
                    int col = nt * 128 + wn + j * 16 + cn;
                    float v = acc[i][j][rr] + e_b1[(size_t)e * HEXP + col];
                    eh[(size_t)entry * HEXP + col] = f2bf(gelu_exact(v));
                }
            }
        }
}

// ---- expert fc2: gathered [cnt,1024] x [1024,512] bf16 GEMM -> per-slot fp32 outs ----
// 1D grid MAXT*2: nt = b&1, ti = b>>1
__global__ __launch_bounds__(512, 4)
void expert_fc2(const u16* __restrict__ eh, const u16* __restrict__ w2t,
                const int* __restrict__ lists, const int* __restrict__ counts,
                const int* __restrict__ tiles, float* __restrict__ outs) {
    int nt = blockIdx.x & 1, ti = blockIdx.x >> 1;
    int info = tiles[ti];
    if (info < 0) return;
    int e = info >> 16, mt = info & 0xFFFF;
    int cnt = counts[e];

    __shared__ u16 lA[128 * BK];
    __shared__ u16 lB[256 * BK];
    __shared__ int rows[128];
    int tt = threadIdx.x;
    if (tt < 128) {
        int m = mt * 128 + tt;
        rows[tt] = lists[(size_t)e * N_TOK + (m < cnt ? m : 0)];
    }
    __syncthreads();

    GEMM_DEFS8

    const u16* wb = w2t + (size_t)e * DMODEL * HEXP + (size_t)(nt * 256) * HEXP;
    const u16* gA[2]; const u16* gB[4];
    #pragma unroll
    for (int i = 0; i < 2; i++)
        gA[i] = eh + (size_t)rows[w * 16 + 8 * i + r8] * HEXP + ce;
    #pragma unroll
    for (int i = 0; i < 4; i++)
        gB[i] = wb + (size_t)(w * 32 + 8 * i + r8) * HEXP + ce;

    for (int k0 = 0; k0 < HEXP; k0 += BK) {
        GEMM_KSTEP8
    }
    int cn = lane & 15;
    #pragma unroll
    for (int i = 0; i < 4; i++)
        #pragma unroll
        for (int rr = 0; rr < 4; rr++) {
            int ml = wm + i * 16 + q4 * 4 + rr;
            int mg = mt * 128 + ml;
            if (mg < cnt) {
                int entry = rows[ml];
                #pragma unroll
                for (int j = 0; j < 4; j++) {
                    int col = nt * 256 + wn + j * 16 + cn;
                    outs[(size_t)entry * DMODEL + col] = acc[i][j][rr];
                }
            }
        }
}

// ---- combine: gate*(outs+b2) + masked residual + final LN ----
__global__ __launch_bounds__(512)
void combine_ln(const float* __restrict__ outs, const float* __restrict__ pgate,
                const int* __restrict__ pexp, const float* __restrict__ e_b2,
                const float* __restrict__ mask, const u16* __restrict__ xhi,
                const u16* __restrict__ xlo, const float* __restrict__ oln_g,
                const float* __restrict__ oln_b, float* __restrict__ out) {
    __shared__ float red[18];
    int n = blockIdx.x, d = threadIdx.x;
    float g0 = pgate[n * 2], g1 = pgate[n * 2 + 1];
    int e0 = pexp[n * 2], e1 = pexp[n * 2 + 1];
    float o = g0 * (outs[(size_t)(n * 2) * DMODEL + d] + e_b2[(size_t)e0 * DMODEL + d])
            + g1 * (outs[(size_t)(n * 2 + 1) * DMODEL + d] + e_b2[(size_t)e1 * DMODEL + d]);
    float m0 = mask[n * 3 + 0], m1 = mask[n * 3 + 1], m2 = mask[n * 3 + 2];
    float denom = fmaxf(m0 + m1 + m2, 1.f);
    size_t xb = (size_t)n * KP;
    float z1n = bf2f(xhi[xb + d]) + bf2f(xlo[xb + d]);                       // hi+lo = fp32-exact
    float z2n = bf2f(xhi[xb + DMODEL + d]) + bf2f(xlo[xb + DMODEL + d]);
    float z3n = bf2f(xhi[xb + 2 * DMODEL + d]) + bf2f(xlo[xb + 2 * DMODEL + d]);
    float z = o + (m0 * z1n + m1 * z2n + m2 * z3n) / denom;
    float2 st = bstats512(z, d, red);
    out[(size_t)n * DMODEL + d] = (z - st.x) * st.y * oln_g[d] + oln_b[d];
}

extern "C" void kernel_launch(void* const* d_in, const int* in_sizes, int n_in,
                              void* d_out, int out_size, void* d_ws, size_t ws_size,
                              hipStream_t stream) {
    (void)in_sizes; (void)n_in; (void)out_size; (void)ws_size;
    const float* z1       = (const float*)d_in[0];
    const float* z2       = (const float*)d_in[1];
    const float* z3       = (const float*)d_in[2];
    const float* mask     = (const float*)d_in[3];
    const float* ln_g     = (const float*)d_in[4];
    const float* ln_b     = (const float*)d_in[5];
    const float* lnp_g    = (const float*)d_in[6];
    const float* lnp_b    = (const float*)d_in[7];
    const float* oln_g    = (const float*)d_in[8];
    const float* oln_b    = (const float*)d_in[9];
    const float* r_w1     = (const float*)d_in[10];
    const float* r_b1     = (const float*)d_in[11];
    const float* r_w2     = (const float*)d_in[12];
    const float* r_b2     = (const float*)d_in[13];
    const float* log_temp = (const float*)d_in[14];
    const float* e_w1     = (const float*)d_in[15];
    const float* e_b1     = (const float*)d_in[16];
    const float* e_w2     = (const float*)d_in[17];
    const float* e_b2     = (const float*)d_in[18];
    float* out = (float*)d_out;

    char* p = (char*)d_ws;
    auto carve = [&](size_t bytes) { char* r = p; p += (bytes + 255) & ~(size_t)255; return r; };
    u16*   xhi    = (u16*)carve((size_t)N_TOK * KP * 2);
    u16*   xlo    = (u16*)carve((size_t)N_TOK * KP * 2);
    u16*   w1t    = (u16*)carve((size_t)NEXP * HEXP * KP * 2);
    u16*   w2t    = (u16*)carve((size_t)NEXP * DMODEL * HEXP * 2);
    u16*   rw1hi  = (u16*)carve((size_t)RHDIM * KP * 2);
    u16*   rw1lo  = (u16*)carve((size_t)RHDIM * KP * 2);
    float* rpart  = (float*)carve((size_t)6 * N_TOK * RHDIM * 4);
    u16*   eh     = (u16*)carve((size_t)NPAIR * HEXP * 2);
    float* outsb  = (float*)carve((size_t)NPAIR * DMODEL * 4);
    float* pgate  = (float*)carve((size_t)NPAIR * 4);
    int*   pexp   = (int*)carve((size_t)NPAIR * 4);
    int*   lists  = (int*)carve((size_t)NEXP * N_TOK * 4);
    int*   counts = (int*)carve(256);
    int*   tiles  = (int*)carve(MAXT * 4);

    dim3 tb(32, 8);
    transpose_f32_bf16<<<dim3(KP / 32, HEXP / 32, NEXP), tb, 0, stream>>>(
        e_w1, w1t, (u16*)nullptr, IN_REAL, KP, HEXP, (size_t)IN_REAL * HEXP, (size_t)HEXP * KP);
    transpose_f32_bf16<<<dim3(HEXP / 32, DMODEL / 32, NEXP), tb, 0, stream>>>(
        e_w2, w2t, (u16*)nullptr, HEXP, HEXP, DMODEL, (size_t)HEXP * DMODEL, (size_t)DMODEL * HEXP);
    transpose_f32_bf16<<<dim3(KP / 32, RHDIM / 32, 1), tb, 0, stream>>>(
        r_w1, rw1hi, rw1lo, IN_REAL, KP, RHDIM, (size_t)0, (size_t)0);

    build_x<<<N_TOK, 512, 0, stream>>>(z1, z2, z3, mask, ln_g, ln_b, lnp_g, lnp_b, xhi, xlo);

    router_fc1<<<384, 512, 0, stream>>>(xhi, xlo, rw1hi, rw1lo, rpart);

    hipMemsetAsync(counts, 0, 256, stream);
    logits_topk<<<N_TOK / 4, 256, 0, stream>>>(rpart, r_b1, r_w2, r_b2, log_temp,
                                               pgate, pexp, lists, counts);
    sched_tiles<<<1, 64, 0, stream>>>(counts, tiles);

    expert_fc1<<<MAXT * 8, 256, 0, stream>>>(xhi, w1t, e_b1, lists, counts, tiles, eh);
    expert_fc2<<<MAXT * 2, 512, 0, stream>>>(eh, w2t, lists, counts, tiles, outsb);

    combine_ln<<<N_TOK, 512, 0, stream>>>(outsb, pgate, pexp, e_b2, mask, xhi, xlo, oln_g, oln_b, out);
}

// Round 6
// 923.494 us; speedup vs baseline: 1.1613x; 1.0591x over previous
//
#include <hip/hip_runtime.h>
#include <math.h>

#define N_TOK 8192
#define DMODEL 512
#define NEXP 8
#define HEXP 1024
#define RHDIM 256
#define KP 4672          // IN_DIM=4611 padded to multiple of 64 (zero-filled)
#define IN_REAL 4611
#define BK 64            // K-tile; one LDS row = 128 B = one cache line
#define NPAIR (N_TOK * 2)
#define MAXT 136         // max expert tiles
#define NRPART 8         // router partial count (4 hh K-chunks + 2 hl + 2 lh)

typedef unsigned short u16;
typedef __bf16 bf16x8 __attribute__((ext_vector_type(8)));
typedef float f32x4 __attribute__((ext_vector_type(4)));

__device__ inline u16 f2bf(float f) {
    union { float f; unsigned u; } x; x.f = f;
    unsigned r = x.u + 0x7FFFu + ((x.u >> 16) & 1u);   // round-to-nearest-even
    return (u16)(r >> 16);
}
__device__ inline float bf2f(u16 u) {
    union { unsigned u; float f; } x; x.u = ((unsigned)u) << 16;
    return x.f;
}
__device__ inline float gelu_exact(float v) {
    return 0.5f * v * (1.f + erff(v * 0.70710678118654752440f));
}

// async global->LDS, 16B per lane; lds base wave-uniform, lane lands at base + lane*16
__device__ inline void async_cp16(const u16* g, u16* l) {
    __builtin_amdgcn_global_load_lds(
        (const __attribute__((address_space(1))) unsigned int*)g,
        (__attribute__((address_space(3))) unsigned int*)l, 16, 0, 0);
}

// ---- multi-stat reduction for 128-thread (2-wave) blocks: v[i] -> block sum ----
// red must hold 2*M floats.
template<int M>
__device__ inline void bred128(float (&v)[M], int t, float* red) {
    #pragma unroll
    for (int o = 32; o > 0; o >>= 1)
        #pragma unroll
        for (int i = 0; i < M; i++) v[i] += __shfl_xor(v[i], o);
    __syncthreads();                        // guard red[] reuse
    if ((t & 63) == 0) {
        #pragma unroll
        for (int i = 0; i < M; i++) red[(t >> 6) * M + i] = v[i];
    }
    __syncthreads();
    #pragma unroll
    for (int i = 0; i < M; i++) v[i] = red[i] + red[M + i];
}

// ---- transpose fp32 [K0,H] -> bf16 [H,KPd] (zero-fill k>=K0), optional hi/lo split ----
// store phase vectorized: each thread writes 4 consecutive k as ushort4 (8B)
__global__ __launch_bounds__(256)
void transpose_f32_bf16(const float* __restrict__ src, u16* __restrict__ dhi, u16* __restrict__ dlo,
                        int K0, int KPd, int H, size_t sbatch, size_t dbatch) {
    __shared__ float tile[32][33];
    int bz = blockIdx.z;
    src += (size_t)bz * sbatch;
    size_t dob = (size_t)bz * dbatch;
    int k0 = blockIdx.x * 32, h0 = blockIdx.y * 32;
    int tx = threadIdx.x, ty = threadIdx.y;
    for (int i = ty; i < 32; i += 8) {
        int k = k0 + i;
        tile[i][tx] = (k < K0) ? src[(size_t)k * H + (h0 + tx)] : 0.f;
    }
    __syncthreads();
    int tid = ty * 32 + tx;
    int h = tid >> 3, kq = tid & 7;          // h in [0,32), kq in [0,8): 4 k's each
    int hg = h0 + h, kg = k0 + kq * 4;
    ushort4 hv, lv;
    float v0 = tile[kq * 4 + 0][h], v1 = tile[kq * 4 + 1][h];
    float v2 = tile[kq * 4 + 2][h], v3 = tile[kq * 4 + 3][h];
    hv.x = f2bf(v0); hv.y = f2bf(v1); hv.z = f2bf(v2); hv.w = f2bf(v3);
    *(ushort4*)(dhi + dob + (size_t)hg * KPd + kg) = hv;
    if (dlo) {
        lv.x = f2bf(v0 - bf2f(hv.x)); lv.y = f2bf(v1 - bf2f(hv.y));
        lv.z = f2bf(v2 - bf2f(hv.z)); lv.w = f2bf(v3 - bf2f(hv.w));
        *(ushort4*)(dlo + dob + (size_t)hg * KPd + kg) = lv;
    }
}

// ---- build fusion input x (9 LayerNorms + mask), emit bf16 hi/lo split ----
// 128 threads x 4 elems: float4 loads, ushort4 stores (G13)
__global__ __launch_bounds__(128)
void build_x(const float* __restrict__ z1, const float* __restrict__ z2, const float* __restrict__ z3,
             const float* __restrict__ mask,
             const float* __restrict__ ln_g, const float* __restrict__ ln_b,
             const float* __restrict__ lnp_g, const float* __restrict__ lnp_b,
             u16* __restrict__ xhi, u16* __restrict__ xlo) {
    __shared__ float red[24];
    int n = blockIdx.x, t = threadIdx.x;
    int d0 = t * 4;
    float4 a4 = ((const float4*)(z1 + (size_t)n * DMODEL))[t];
    float4 b4 = ((const float4*)(z2 + (size_t)n * DMODEL))[t];
    float4 c4 = ((const float4*)(z3 + (size_t)n * DMODEL))[t];
    float a[4] = {a4.x, a4.y, a4.z, a4.w};
    float b[4] = {b4.x, b4.y, b4.z, b4.w};
    float c[4] = {c4.x, c4.y, c4.z, c4.w};
    float4 gg4 = ((const float4*)ln_g)[t], bb4 = ((const float4*)ln_b)[t];
    float4 pg4 = ((const float4*)lnp_g)[t], pb4 = ((const float4*)lnp_b)[t];
    float gg[4] = {gg4.x, gg4.y, gg4.z, gg4.w}, bb[4] = {bb4.x, bb4.y, bb4.z, bb4.w};
    float pg[4] = {pg4.x, pg4.y, pg4.z, pg4.w}, pb[4] = {pb4.x, pb4.y, pb4.z, pb4.w};
    size_t base = (size_t)n * KP;

    auto emit = [&](int seg, const float* v) {
        ushort4 hv, lv;
        hv.x = f2bf(v[0]); hv.y = f2bf(v[1]); hv.z = f2bf(v[2]); hv.w = f2bf(v[3]);
        lv.x = f2bf(v[0] - bf2f(hv.x)); lv.y = f2bf(v[1] - bf2f(hv.y));
        lv.z = f2bf(v[2] - bf2f(hv.z)); lv.w = f2bf(v[3] - bf2f(hv.w));
        *(ushort4*)(xhi + base + seg * DMODEL + d0) = hv;
        *(ushort4*)(xlo + base + seg * DMODEL + d0) = lv;
    };
    // phase 1: three base LNs in one reduction round
    float v6[6] = {0.f, 0.f, 0.f, 0.f, 0.f, 0.f};
    #pragma unroll
    for (int j = 0; j < 4; j++) {
        v6[0] += a[j]; v6[1] += a[j] * a[j];
        v6[2] += b[j]; v6[3] += b[j] * b[j];
        v6[4] += c[j]; v6[5] += c[j] * c[j];
    }
    bred128<6>(v6, t, red);
    auto lnstats = [](float s, float q, float* m, float* r) {
        *m = s * (1.f / 512.f);
        float var = fmaxf(q * (1.f / 512.f) - (*m) * (*m), 0.f);
        *r = rsqrtf(var + 1e-5f);
    };
    float m1, r1, m2, r2, m3, r3;
    lnstats(v6[0], v6[1], &m1, &r1);
    lnstats(v6[2], v6[3], &m2, &r2);
    lnstats(v6[4], v6[5], &m3, &r3);
    float za[4], zb[4], zc[4];
    #pragma unroll
    for (int j = 0; j < 4; j++) {
        za[j] = (a[j] - m1) * r1 * gg[j] + bb[j];
        zb[j] = (b[j] - m2) * r2 * gg[j] + bb[j];
        zc[j] = (c[j] - m3) * r3 * gg[j] + bb[j];
    }
    emit(0, za); emit(1, zb); emit(2, zc);
    // phase 2: six pair LNs in one reduction round
    float d12[4], d13[4], d23[4], p12[4], p13[4], p23[4];
    float v12[12];
    #pragma unroll
    for (int i = 0; i < 12; i++) v12[i] = 0.f;
    #pragma unroll
    for (int j = 0; j < 4; j++) {
        d12[j] = za[j] - zb[j]; d13[j] = za[j] - zc[j]; d23[j] = zb[j] - zc[j];
        p12[j] = za[j] * zb[j]; p13[j] = za[j] * zc[j]; p23[j] = zb[j] * zc[j];
        v12[0] += d12[j]; v12[1] += d12[j] * d12[j];
        v12[2] += d13[j]; v12[3] += d13[j] * d13[j];
        v12[4] += d23[j]; v12[5] += d23[j] * d23[j];
        v12[6] += p12[j]; v12[7] += p12[j] * p12[j];
        v12[8] += p13[j]; v12[9] += p13[j] * p13[j];
        v12[10] += p23[j]; v12[11] += p23[j] * p23[j];
    }
    bred128<12>(v12, t, red);
    float* segs[6] = {d12, d13, d23, p12, p13, p23};
    #pragma unroll
    for (int s = 0; s < 6; s++) {
        float ms, rs;
        lnstats(v12[s * 2], v12[s * 2 + 1], &ms, &rs);
        float v[4];
        #pragma unroll
        for (int j = 0; j < 4; j++) v[j] = (segs[s][j] - ms) * rs * pg[j] + pb[j];
        emit(3 + s, v);
    }
    if (t < 16) {   // mask cols 4608..4610 + zero pad 4611..4671
        float v[4] = {0.f, 0.f, 0.f, 0.f};
        if (t == 0) { v[0] = mask[(size_t)n * 3]; v[1] = mask[(size_t)n * 3 + 1]; v[2] = mask[(size_t)n * 3 + 2]; }
        ushort4 hv, lv;
        hv.x = f2bf(v[0]); hv.y = f2bf(v[1]); hv.z = f2bf(v[2]); hv.w = f2bf(v[3]);
        lv.x = f2bf(v[0] - bf2f(hv.x)); lv.y = f2bf(v[1] - bf2f(hv.y));
        lv.z = f2bf(v[2] - bf2f(hv.z)); lv.w = f2bf(v[3] - bf2f(hv.w));
        *(ushort4*)(xhi + base + 9 * DMODEL + t * 4) = hv;
        *(ushort4*)(xlo + base + 9 * DMODEL + t * 4) = lv;
    }
}

// ========== r0-proven 128x128 bf16 GEMM, BK=64, 256 threads (4 waves, 2x2) ==========
#define GEMM_DEFS4                                                            \
    int t = threadIdx.x;                                                      \
    int lane = t & 63, w = t >> 6;                                            \
    int r8 = lane >> 3;                                                       \
    int ce = ((lane & 7) ^ r8) * 8;       /* swizzled global chunk, elems */  \
    int fr = lane & 15, q4 = lane >> 4;                                       \
    int wm = (w & 1) * 64, wn = (w >> 1) * 64;                                \
    f32x4 acc[4][4];                                                          \
    { f32x4 z4 = {0.f, 0.f, 0.f, 0.f};                                        \
      _Pragma("unroll") for (int i = 0; i < 4; i++)                           \
      _Pragma("unroll") for (int j = 0; j < 4; j++) acc[i][j] = z4; }         \
    u16 *lAp[4], *lBp[4];                                                     \
    _Pragma("unroll") for (int i = 0; i < 4; i++) {                           \
        lAp[i] = lA + (w * 32 + 8 * i) * BK;                                  \
        lBp[i] = lB + (w * 32 + 8 * i) * BK;                                  \
    }

#define GEMM_KSTEP4                                                           \
        __syncthreads();                                                      \
        _Pragma("unroll") for (int i = 0; i < 4; i++) {                       \
            async_cp16(gA[i], lAp[i]); async_cp16(gB[i], lBp[i]);             \
            gA[i] += BK; gB[i] += BK;                                         \
        }                                                                     \
        __syncthreads();                                                      \
        _Pragma("unroll") for (int ks = 0; ks < 2; ks++) {                    \
            bf16x8 af[4], bfr[4];                                             \
            int cofs = (((q4 + ks * 4) ^ (fr & 7)) * 8);                      \
            _Pragma("unroll") for (int i = 0; i < 4; i++)                     \
                af[i] = *(const bf16x8*)&lA[(wm + i * 16 + fr) * BK + cofs];  \
            _Pragma("unroll") for (int j = 0; j < 4; j++)                     \
                bfr[j] = *(const bf16x8*)&lB[(wn + j * 16 + fr) * BK + cofs]; \
            _Pragma("unroll") for (int i = 0; i < 4; i++)                     \
            _Pragma("unroll") for (int j = 0; j < 4; j++)                     \
                acc[i][j] = __builtin_amdgcn_mfma_f32_16x16x32_bf16(af[i], bfr[j], acc[i][j], 0, 0, 0); \
        }

// ===== r2-proven 128x256 bf16 GEMM, BK=64, 512 threads (8 waves, 2Mx4N) =====
#define GEMM_DEFS8                                                            \
    int t = threadIdx.x;                                                      \
    int lane = t & 63, w = t >> 6;                                            \
    int r8 = lane >> 3;                                                       \
    int ce = ((lane & 7) ^ r8) * 8;       /* swizzled global chunk, elems */  \
    int fr = lane & 15, q4 = lane >> 4;                                       \
    int wm = (w & 1) * 64, wn = (w >> 1) * 64;                                \
    f32x4 acc[4][4];                                                          \
    { f32x4 z4 = {0.f, 0.f, 0.f, 0.f};                                        \
      _Pragma("unroll") for (int i = 0; i < 4; i++)                           \
      _Pragma("unroll") for (int j = 0; j < 4; j++) acc[i][j] = z4; }         \
    u16 *lAp[2], *lBp[4];                                                     \
    _Pragma("unroll") for (int i = 0; i < 2; i++)                             \
        lAp[i] = lA + (w * 16 + 8 * i) * BK;                                  \
    _Pragma("unroll") for (int i = 0; i < 4; i++)                             \
        lBp[i] = lB + (w * 32 + 8 * i) * BK;

#define GEMM_KSTEP8                                                           \
        __syncthreads();                                                      \
        _Pragma("unroll") for (int i = 0; i < 2; i++) {                       \
            async_cp16(gA[i], lAp[i]); gA[i] += BK;                           \
        }                                                                     \
        _Pragma("unroll") for (int i = 0; i < 4; i++) {                       \
            async_cp16(gB[i], lBp[i]); gB[i] += BK;                           \
        }                                                                     \
        __syncthreads();                                                      \
        _Pragma("unroll") for (int ks = 0; ks < 2; ks++) {                    \
            bf16x8 af[4], bfr[4];                                             \
            int cofs = (((q4 + ks * 4) ^ (fr & 7)) * 8);                      \
            _Pragma("unroll") for (int i = 0; i < 4; i++)                     \
                af[i] = *(const bf16x8*)&lA[(wm + i * 16 + fr) * BK + cofs];  \
            _Pragma("unroll") for (int j = 0; j < 4; j++)                     \
                bfr[j] = *(const bf16x8*)&lB[(wn + j * 16 + fr) * BK + cofs]; \
            _Pragma("unroll") for (int i = 0; i < 4; i++)                     \
            _Pragma("unroll") for (int j = 0; j < 4; j++)                     \
                acc[i][j] = __builtin_amdgcn_mfma_f32_16x16x32_bf16(af[i], bfr[j], acc[i][j], 0, 0, 0); \
        }

// ---- router fc1: partial GEMM; 1D grid 512: mt = b&63, part = b>>6 in [0,8) ----
// 8 K-balanced parts: hh (4 chunks: 1152/1152/1152/1216), hl (2304/2368), lh (2304/2368)
// -> 512 blocks = exactly 2 blocks/CU, one balanced round (was 384 blocks: half the CUs
// ran 2 sequential blocks while the rest idled -> ~2x wall).
__global__ __launch_bounds__(512, 4)
void router_fc1(const u16* __restrict__ xhi, const u16* __restrict__ xlo,
                const u16* __restrict__ rw1hi, const u16* __restrict__ rw1lo,
                float* __restrict__ rpart) {
    int mt = blockIdx.x & 63, part = blockIdx.x >> 6;
    const u16* A; const u16* B;
    int kbase, klen;
    if (part < 4) {            // hi*hi in 4 K-chunks
        A = xhi; B = rw1hi;
        kbase = part * 1152;
        klen = (part == 3) ? 1216 : 1152;
    } else {
        int half = part & 1;
        kbase = half ? 2304 : 0;
        klen  = half ? 2368 : 2304;
        if (part < 6) { A = xhi; B = rw1lo; }   // hi*lo
        else          { A = xlo; B = rw1hi; }   // lo*hi
    }

    __shared__ u16 lA[128 * BK];
    __shared__ u16 lB[256 * BK];
    GEMM_DEFS8

    const u16* gA[2]; const u16* gB[4];
    #pragma unroll
    for (int i = 0; i < 2; i++)
        gA[i] = A + (size_t)(mt * 128 + w * 16 + 8 * i + r8) * KP + kbase + ce;
    #pragma unroll
    for (int i = 0; i < 4; i++)
        gB[i] = B + (size_t)(w * 32 + 8 * i + r8) * KP + kbase + ce;

    for (int k0 = 0; k0 < klen; k0 += BK) {
        GEMM_KSTEP8
    }
    float* outp = rpart + (size_t)part * ((size_t)N_TOK * RHDIM);
    int cn = lane & 15;
    #pragma unroll
    for (int i = 0; i < 4; i++)
        #pragma unroll
        for (int rr = 0; rr < 4; rr++) {
            int mg = mt * 128 + wm + i * 16 + q4 * 4 + rr;
            #pragma unroll
            for (int j = 0; j < 4; j++)
                outp[(size_t)mg * RHDIM + wn + j * 16 + cn] = acc[i][j][rr];
        }
}

// ---- fused: partial-sum + bias + gelu + logits + top-2 + gates + scatter (1 wave/token) ----
__global__ __launch_bounds__(256)
void logits_topk(const float* __restrict__ rpart, const float* __restrict__ r_b1,
                 const float* __restrict__ r_w2, const float* __restrict__ r_b2,
                 const float* __restrict__ log_temp,
                 float* __restrict__ pgate, int* __restrict__ pexp,
                 int* __restrict__ lists, int* __restrict__ counts) {
    int t = threadIdx.x, wave = t >> 6, lane = t & 63;
    int n = blockIdx.x * 4 + wave;
    // each lane owns rh cols lane*4..lane*4+3
    float4 v = {0.f, 0.f, 0.f, 0.f};
    #pragma unroll
    for (int p = 0; p < NRPART; p++) {
        float4 s = ((const float4*)(rpart + (size_t)p * ((size_t)N_TOK * RHDIM) + (size_t)n * RHDIM))[lane];
        v.x += s.x; v.y += s.y; v.z += s.z; v.w += s.w;
    }
    float4 b1 = ((const float4*)r_b1)[lane];
    float rh0 = gelu_exact(v.x + b1.x);
    float rh1 = gelu_exact(v.y + b1.y);
    float rh2 = gelu_exact(v.z + b1.z);
    float rh3 = gelu_exact(v.w + b1.w);
    int k = lane * 4;
    float p8[8];
    #pragma unroll
    for (int e = 0; e < 8; e++)
        p8[e] = rh0 * r_w2[(k + 0) * 8 + e] + rh1 * r_w2[(k + 1) * 8 + e]
              + rh2 * r_w2[(k + 2) * 8 + e] + rh3 * r_w2[(k + 3) * 8 + e];
    #pragma unroll
    for (int o = 32; o > 0; o >>= 1)
        #pragma unroll
        for (int e = 0; e < 8; e++) p8[e] += __shfl_xor(p8[e], o);
    if (lane == 0) {
        float temp = fminf(fmaxf(expf(log_temp[0]), 1e-3f), 100.f);
        float l[8];
        #pragma unroll
        for (int e = 0; e < 8; e++) l[e] = (p8[e] + r_b2[e]) / temp;
        int i1 = 0;
        #pragma unroll
        for (int i = 1; i < 8; i++) if (l[i] > l[i1]) i1 = i;   // first-occurrence max (matches top_k)
        int i2 = (i1 == 0) ? 1 : 0;
        #pragma unroll
        for (int i = 0; i < 8; i++) if (i != i1 && l[i] > l[i2]) i2 = i;
        float p = expf(l[i2] - l[i1]);
        float g1 = 1.f / (1.f + p);
        float g2 = p / (1.f + p);
        pgate[n * 2] = g1;     pexp[n * 2] = i1;
        pgate[n * 2 + 1] = g2; pexp[n * 2 + 1] = i2;
        int pos1 = atomicAdd(&counts[i1], 1);
        lists[(size_t)i1 * N_TOK + pos1] = n * 2;
        int pos2 = atomicAdd(&counts[i2], 1);
        lists[(size_t)i2 * N_TOK + pos2] = n * 2 + 1;
    }
}

// ---- tile scheduler: counts -> compact (e,mt) list, expert-major ----
__global__ void sched_tiles(const int* __restrict__ counts, int* __restrict__ tiles) {
    if (threadIdx.x == 0) {
        int tcount = 0;
        for (int e = 0; e < NEXP; e++) {
            int nt = (counts[e] + 127) >> 7;
            for (int mt = 0; mt < nt; mt++) tiles[tcount++] = (e << 16) | mt;
        }
        for (; tcount < MAXT; tcount++) tiles[tcount] = -1;   // sentinel
    }
}

// ---- expert fc1: gathered [cnt,KP] x [KP,1024] bf16 GEMM, gelu -> eh bf16 ----
// 1D grid MAXT*8: nt = b&7, ti = b>>3  (blocks 8 apart: same XCD, same nt, next tile)
__global__ __launch_bounds__(256, 4)
void expert_fc1(const u16* __restrict__ xhi, const u16* __restrict__ w1t,
                const float* __restrict__ e_b1, const int* __restrict__ lists,
                const int* __restrict__ counts, const int* __restrict__ tiles,
                u16* __restrict__ eh) {
    int nt = blockIdx.x & 7, ti = blockIdx.x >> 3;
    int info = tiles[ti];
    if (info < 0) return;
    int e = info >> 16, mt = info & 0xFFFF;
    int cnt = counts[e];

    __shared__ u16 lA[128 * BK];
    __shared__ u16 lB[128 * BK];
    __shared__ int rows[128];
    int tt = threadIdx.x;
    if (tt < 128) {
        int m = mt * 128 + tt;
        rows[tt] = lists[(size_t)e * N_TOK + (m < cnt ? m : 0)];   // clamp tail to valid entry
    }
    __syncthreads();

    GEMM_DEFS4

    const u16* wb = w1t + (size_t)e * HEXP * KP + (size_t)(nt * 128) * KP;
    const u16* gA[4]; const u16* gB[4];
    #pragma unroll
    for (int i = 0; i < 4; i++) {
        gA[i] = xhi + (size_t)(rows[w * 32 + 8 * i + r8] >> 1) * KP + ce;
        gB[i] = wb + (size_t)(w * 32 + 8 * i + r8) * KP + ce;
    }

    for (int k0 = 0; k0 < KP; k0 += BK) {
        GEMM_KSTEP4
    }
    int cn = lane & 15;
    #pragma unroll
    for (int i = 0; i < 4; i++)
        #pragma unroll
        for (int rr = 0; rr < 4; rr++) {
            int ml = wm + i * 16 + q4 * 4 + rr;
            int mg = mt * 128 + ml;
            if (mg < cnt) {
                int entry = rows[ml];
                #pragma unroll
                for (int j = 0; j < 4; j++) {
                    int col = nt * 128 + wn + j * 16 + cn;
                    float v = acc[i][j][rr] + e_b1[(size_t)e * HEXP + col];
                    eh[(size_t)entry * HEXP + col] = f2bf(gelu_exact(v));
                }
            }
        }
}

// ---- expert fc2: gathered [cnt,1024] x [1024,512] bf16 GEMM -> per-slot fp32 outs ----
// 1D grid MAXT*2: nt = b&1, ti = b>>1
__global__ __launch_bounds__(512, 4)
void expert_fc2(const u16* __restrict__ eh, const u16* __restrict__ w2t,
                const int* __restrict__ lists, const int* __restrict__ counts,
                const int* __restrict__ tiles, float* __restrict__ outs) {
    int nt = blockIdx.x & 1, ti = blockIdx.x >> 1;
    int info = tiles[ti];
    if (info < 0) return;
    int e = info >> 16, mt = info & 0xFFFF;
    int cnt = counts[e];

    __shared__ u16 lA[128 * BK];
    __shared__ u16 lB[256 * BK];
    __shared__ int rows[128];
    int tt = threadIdx.x;
    if (tt < 128) {
        int m = mt * 128 + tt;
        rows[tt] = lists[(size_t)e * N_TOK + (m < cnt ? m : 0)];
    }
    __syncthreads();

    GEMM_DEFS8

    const u16* wb = w2t + (size_t)e * DMODEL * HEXP + (size_t)(nt * 256) * HEXP;
    const u16* gA[2]; const u16* gB[4];
    #pragma unroll
    for (int i = 0; i < 2; i++)
        gA[i] = eh + (size_t)rows[w * 16 + 8 * i + r8] * HEXP + ce;
    #pragma unroll
    for (int i = 0; i < 4; i++)
        gB[i] = wb + (size_t)(w * 32 + 8 * i + r8) * HEXP + ce;

    for (int k0 = 0; k0 < HEXP; k0 += BK) {
        GEMM_KSTEP8
    }
    int cn = lane & 15;
    #pragma unroll
    for (int i = 0; i < 4; i++)
        #pragma unroll
        for (int rr = 0; rr < 4; rr++) {
            int ml = wm + i * 16 + q4 * 4 + rr;
            int mg = mt * 128 + ml;
            if (mg < cnt) {
                int entry = rows[ml];
                #pragma unroll
                for (int j = 0; j < 4; j++) {
                    int col = nt * 256 + wn + j * 16 + cn;
                    outs[(size_t)entry * DMODEL + col] = acc[i][j][rr];
                }
            }
        }
}

// ---- combine: gate*(outs+b2) + masked residual + final LN ----
// 128 threads x 4 elems: float4/ushort4 loads, float4 store
__global__ __launch_bounds__(128)
void combine_ln(const float* __restrict__ outs, const float* __restrict__ pgate,
                const int* __restrict__ pexp, const float* __restrict__ e_b2,
                const float* __restrict__ mask, const u16* __restrict__ xhi,
                const u16* __restrict__ xlo, const float* __restrict__ oln_g,
                const float* __restrict__ oln_b, float* __restrict__ out) {
    __shared__ float red[4];
    int n = blockIdx.x, t = threadIdx.x;
    float g0 = pgate[n * 2], g1 = pgate[n * 2 + 1];
    int e0 = pexp[n * 2], e1 = pexp[n * 2 + 1];
    float4 o0 = ((const float4*)(outs + (size_t)(n * 2) * DMODEL))[t];
    float4 o1 = ((const float4*)(outs + (size_t)(n * 2 + 1) * DMODEL))[t];
    float4 b0 = ((const float4*)(e_b2 + (size_t)e0 * DMODEL))[t];
    float4 b1 = ((const float4*)(e_b2 + (size_t)e1 * DMODEL))[t];
    float o[4] = {g0 * (o0.x + b0.x) + g1 * (o1.x + b1.x),
                  g0 * (o0.y + b0.y) + g1 * (o1.y + b1.y),
                  g0 * (o0.z + b0.z) + g1 * (o1.z + b1.z),
                  g0 * (o0.w + b0.w) + g1 * (o1.w + b1.w)};
    float m0 = mask[n * 3 + 0], m1 = mask[n * 3 + 1], m2 = mask[n * 3 + 2];
    float denom = fmaxf(m0 + m1 + m2, 1.f);
    size_t xb = (size_t)n * KP;
    ushort4 h1 = *(const ushort4*)(xhi + xb + t * 4);
    ushort4 l1 = *(const ushort4*)(xlo + xb + t * 4);
    ushort4 h2 = *(const ushort4*)(xhi + xb + DMODEL + t * 4);
    ushort4 l2 = *(const ushort4*)(xlo + xb + DMODEL + t * 4);
    ushort4 h3 = *(const ushort4*)(xhi + xb + 2 * DMODEL + t * 4);
    ushort4 l3 = *(const ushort4*)(xlo + xb + 2 * DMODEL + t * 4);
    float z[4], s = 0.f, q = 0.f;
    u16 h1a[4] = {h1.x, h1.y, h1.z, h1.w}, l1a[4] = {l1.x, l1.y, l1.z, l1.w};
    u16 h2a[4] = {h2.x, h2.y, h2.z, h2.w}, l2a[4] = {l2.x, l2.y, l2.z, l2.w};
    u16 h3a[4] = {h3.x, h3.y, h3.z, h3.w}, l3a[4] = {l3.x, l3.y, l3.z, l3.w};
    #pragma unroll
    for (int j = 0; j < 4; j++) {
        float z1n = bf2f(h1a[j]) + bf2f(l1a[j]);
        float z2n = bf2f(h2a[j]) + bf2f(l2a[j]);
        float z3n = bf2f(h3a[j]) + bf2f(l3a[j]);
        z[j] = o[j] + (m0 * z1n + m1 * z2n + m2 * z3n) / denom;
        s += z[j]; q += z[j] * z[j];
    }
    // 2-wave reduction
    #pragma unroll
    for (int ofs = 32; ofs > 0; ofs >>= 1) {
        s += __shfl_xor(s, ofs);
        q += __shfl_xor(q, ofs);
    }
    if ((t & 63) == 0) { red[(t >> 6) * 2] = s; red[(t >> 6) * 2 + 1] = q; }
    __syncthreads();
    s = red[0] + red[2]; q = red[1] + red[3];
    float m = s * (1.f / 512.f);
    float var = fmaxf(q * (1.f / 512.f) - m * m, 0.f);
    float r = rsqrtf(var + 1e-5f);
    float4 g4 = ((const float4*)oln_g)[t], be4 = ((const float4*)oln_b)[t];
    float4 res;
    res.x = (z[0] - m) * r * g4.x + be4.x;
    res.y = (z[1] - m) * r * g4.y + be4.y;
    res.z = (z[2] - m) * r * g4.z + be4.z;
    res.w = (z[3] - m) * r * g4.w + be4.w;
    ((float4*)(out + (size_t)n * DMODEL))[t] = res;
}

extern "C" void kernel_launch(void* const* d_in, const int* in_sizes, int n_in,
                              void* d_out, int out_size, void* d_ws, size_t ws_size,
                              hipStream_t stream) {
    (void)in_sizes; (void)n_in; (void)out_size; (void)ws_size;
    const float* z1       = (const float*)d_in[0];
    const float* z2       = (const float*)d_in[1];
    const float* z3       = (const float*)d_in[2];
    const float* mask     = (const float*)d_in[3];
    const float* ln_g     = (const float*)d_in[4];
    const float* ln_b     = (const float*)d_in[5];
    const float* lnp_g    = (const float*)d_in[6];
    const float* lnp_b    = (const float*)d_in[7];
    const float* oln_g    = (const float*)d_in[8];
    const float* oln_b    = (const float*)d_in[9];
    const float* r_w1     = (const float*)d_in[10];
    const float* r_b1     = (const float*)d_in[11];
    const float* r_w2     = (const float*)d_in[12];
    const float* r_b2     = (const float*)d_in[13];
    const float* log_temp = (const float*)d_in[14];
    const float* e_w1     = (const float*)d_in[15];
    const float* e_b1     = (const float*)d_in[16];
    const float* e_w2     = (const float*)d_in[17];
    const float* e_b2     = (const float*)d_in[18];
    float* out = (float*)d_out;

    char* p = (char*)d_ws;
    auto carve = [&](size_t bytes) { char* r = p; p += (bytes + 255) & ~(size_t)255; return r; };
    u16*   xhi    = (u16*)carve((size_t)N_TOK * KP * 2);
    u16*   xlo    = (u16*)carve((size_t)N_TOK * KP * 2);
    u16*   w1t    = (u16*)carve((size_t)NEXP * HEXP * KP * 2);
    u16*   w2t    = (u16*)carve((size_t)NEXP * DMODEL * HEXP * 2);
    u16*   rw1hi  = (u16*)carve((size_t)RHDIM * KP * 2);
    u16*   rw1lo  = (u16*)carve((size_t)RHDIM * KP * 2);
    float* rpart  = (float*)carve((size_t)NRPART * N_TOK * RHDIM * 4);
    u16*   eh     = (u16*)carve((size_t)NPAIR * HEXP * 2);
    float* outsb  = (float*)carve((size_t)NPAIR * DMODEL * 4);
    float* pgate  = (float*)carve((size_t)NPAIR * 4);
    int*   pexp   = (int*)carve((size_t)NPAIR * 4);
    int*   lists  = (int*)carve((size_t)NEXP * N_TOK * 4);
    int*   counts = (int*)carve(256);
    int*   tiles  = (int*)carve(MAXT * 4);

    dim3 tb(32, 8);
    transpose_f32_bf16<<<dim3(KP / 32, HEXP / 32, NEXP), tb, 0, stream>>>(
        e_w1, w1t, (u16*)nullptr, IN_REAL, KP, HEXP, (size_t)IN_REAL * HEXP, (size_t)HEXP * KP);
    transpose_f32_bf16<<<dim3(HEXP / 32, DMODEL / 32, NEXP), tb, 0, stream>>>(
        e_w2, w2t, (u16*)nullptr, HEXP, HEXP, DMODEL, (size_t)HEXP * DMODEL, (size_t)DMODEL * HEXP);
    transpose_f32_bf16<<<dim3(KP / 32, RHDIM / 32, 1), tb, 0, stream>>>(
        r_w1, rw1hi, rw1lo, IN_REAL, KP, RHDIM, (size_t)0, (size_t)0);

    build_x<<<N_TOK, 128, 0, stream>>>(z1, z2, z3, mask, ln_g, ln_b, lnp_g, lnp_b, xhi, xlo);

    router_fc1<<<512, 512, 0, stream>>>(xhi, xlo, rw1hi, rw1lo, rpart);

    hipMemsetAsync(counts, 0, 256, stream);
    logits_topk<<<N_TOK / 4, 256, 0, stream>>>(rpart, r_b1, r_w2, r_b2, log_temp,
                                               pgate, pexp, lists, counts);
    sched_tiles<<<1, 64, 0, stream>>>(counts, tiles);

    expert_fc1<<<MAXT * 8, 256, 0, stream>>>(xhi, w1t, e_b1, lists, counts, tiles, eh);
    expert_fc2<<<MAXT * 2, 512, 0, stream>>>(eh, w2t, lists, counts, tiles, outsb);

    combine_ln<<<N_TOK, 128, 0, stream>>>(outsb, pgate, pexp, e_b2, mask, xhi, xlo, oln_g, oln_b, out);
}